// Round 21
// baseline (106.700 us; speedup 1.0000x reference)
//
#include <hip/hip_runtime.h>
#include <hip/hip_bf16.h>
#include <math.h>

typedef __attribute__((ext_vector_type(8))) short short8;
typedef __attribute__((ext_vector_type(8))) _Float16 f16x8;
typedef __attribute__((ext_vector_type(4))) float f32x4;

__device__ __forceinline__ short f2bf(float x) {
    union { float f; unsigned u; } v; v.f = x;
    unsigned r = v.u + 0x7fffu + ((v.u >> 16) & 1u);   // RNE
    return (short)(r >> 16);
}
__device__ __forceinline__ unsigned cvtpk(float lo, float hi) {
    unsigned r;
    asm("v_cvt_pk_bf16_f32 %0, %1, %2" : "=v"(r) : "v"(lo), "v"(hi));
    return r;
}
__device__ __forceinline__ unsigned pk_addrelu(unsigned a, unsigned b) {
    unsigned r;
    asm("v_pk_add_f16 %0, %1, %2\n\tv_pk_max_f16 %0, %0, 0"
        : "=v"(r) : "v"(a), "v"(b));
    return r;
}
union U32x4 { unsigned u[4]; short8 s8; };
union U32x4H { unsigned u[4]; f16x8 h8; };

// ================================================================ setup + combine (grid 504)
// blk 0..63   : W4P   (u<16)
// blk 64..319 : F1P   (u<16)
// blk 320..447: F2    (u<16)
// blk 448..471: EW2H + PWP (u<16)
// blk 472..503: combine (16-col j-tiles)
__global__ __launch_bounds__(256) void setup_kernel(const float* __restrict__ ew2,
                                                    const float* __restrict__ pw1, const float* __restrict__ pw2,
                                                    const float* __restrict__ nw1, const float* __restrict__ nw2,
                                                    const float* __restrict__ sw, const float* __restrict__ tw,
                                                    const float* __restrict__ sb, const float* __restrict__ tb,
                                                    const float* __restrict__ ew1, const float* __restrict__ eb1,
                                                    short* __restrict__ W4P, short* __restrict__ F1P,
                                                    short* __restrict__ F2, _Float16* __restrict__ EW2H,
                                                    short* __restrict__ PWP,
                                                    short* __restrict__ WCP, float* __restrict__ BC) {
    __shared__ float2 tab[4096];
    __shared__ float eL2[256][16];
    int blk = blockIdx.x, tid = threadIdx.x;
    if (blk < 64) {                                    // W4P (64 blocks)
        for (int i = tid; i < 4096; i += 256) {
            float sn, cs; sincospif((float)i * (1.0f / 2048.0f), &sn, &cs);
            tab[i] = make_float2(cs, sn);
        }
        __syncthreads();
        int base = blk * 4096;
        #pragma unroll 4
        for (int u = 0; u < 16; ++u) {
            int i = base + u * 256 + tid;
            int j = i & 7, lane = (i >> 3) & 63, nf = (i >> 9) & 3, kkg = i >> 11;
            int k = kkg * 32 + (lane >> 4) * 8 + j;
            int n = nf * 16 + (lane & 15);
            float2 cs = tab[(k * (n & 31)) & 4095];
            W4P[i] = f2bf(n < 32 ? cs.x : -cs.y);
        }
    } else if (blk < 320) {                            // F1P (256 blocks)
        for (int i = tid; i < 512; i += 256) {
            float sn, cs; sincospif((float)i * (1.0f / 256.0f), &sn, &cs);
            tab[i] = make_float2(cs, sn);
        }
        __syncthreads();
        int base = (blk - 64) * 4096;
        #pragma unroll 4
        for (int u = 0; u < 16; ++u) {
            int ii = base + u * 256 + tid;
            int j = ii & 7, lane = (ii >> 3) & 63, nfg = (ii >> 9) & 63, kk = ii >> 15;
            int k2 = kk * 32 + (lane >> 4) * 8 + j;
            int t = k2 >> 1, c = k2 & 1;
            int n = nfg * 16 + (lane & 15);
            int q = n >> 1, d = n & 1;
            float2 cs = tab[(t * q) & 511];
            F1P[ii] = f2bf((c == d) ? cs.x : (c ? -cs.y : cs.y));
        }
    } else if (blk < 448) {                            // F2 (128 blocks)
        for (int i = tid; i < 512; i += 256) {
            float sn, cs; sincospif((float)i * (1.0f / 256.0f), &sn, &cs);
            tab[i] = make_float2(cs, sn);
        }
        __syncthreads();
        int base = (blk - 320) * 4096;
        #pragma unroll 4
        for (int u = 0; u < 16; ++u) {
            int ii = base + u * 256 + tid;
            int p = ii >> 10, k2 = ii & 1023;
            int s = k2 >> 1, dd = k2 & 1;
            float2 cs = tab[(p * s) & 511];
            F2[ii] = f2bf(dd ? -cs.y : cs.x);
        }
    } else if (blk < 472) {                            // EW2H (fp16) + PWP (bf16), 24 blocks
        int base = (blk - 448) * 4096;
        #pragma unroll 4
        for (int u = 0; u < 16; ++u) {
            int ii = base + u * 256 + tid;
            if (ii < 32768) {
                int j = ii & 7, lane = (ii >> 3) & 63, hf = (ii >> 9) & 7, kk = ii >> 12;
                int k = kk * 32 + (lane >> 4) * 8 + j;
                int h = hf * 16 + (lane & 15);
                EW2H[ii] = (_Float16)ew2[k * 128 + h];
            } else {
                int iw = ii - 32768;
                int l = iw >> 14;
                int r = iw & 16383;
                int j = r & 7, lane = (r >> 3) & 63, nf = (r >> 9) & 7, kk = r >> 12;
                int k = kk * 32 + (lane >> 4) * 8 + j;
                int n = nf * 16 + (lane & 15);
                const float* W = (l == 0) ? pw1 : (l == 1) ? pw2 : (l == 2) ? nw1 : nw2;
                PWP[iw] = f2bf(W[k * 128 + n]);
            }
        }
    } else {                                           // combine (32 blocks, 16-col tiles)
        int blk2 = blk - 472;                          // 0..31
        int half = blk2 >> 4, jt = blk2 & 15, j0 = jt * 16;
        const float* ebase = ew1 + (size_t)half * 256 * 256;
        #pragma unroll
        for (int it = 0; it < 16; ++it) {
            int idx = tid + it * 256;                  // 4096 = 256 rows x 16 cols
            int i = idx >> 4, jj = idx & 15;
            eL2[i][jj] = ebase[(size_t)i * 256 + j0 + jj];
        }
        __syncthreads();
        const float* wp = half ? tw : sw;
        int d = tid >> 1, jh = tid & 1;
        float acc[8];
        #pragma unroll
        for (int x = 0; x < 8; ++x) acc[x] = 0.f;
        #pragma unroll 4
        for (int i = 0; i < 256; ++i) {
            float wv = wp[(size_t)d * 256 + i];
            #pragma unroll
            for (int x = 0; x < 8; ++x) acc[x] += wv * eL2[i][jh * 8 + x];
        }
        int kk = d >> 5, lg = (d >> 3) & 3, j = d & 7;
        #pragma unroll
        for (int x = 0; x < 8; ++x) {
            int n = half * 256 + j0 + jh * 8 + x;
            int lane = lg * 16 + (n & 15);
            WCP[((kk * 32 + (n >> 4)) * 64 + lane) * 8 + j] = f2bf(acc[x]);
        }
        if (tid < 16) {
            const float* bv = half ? tb : sb;
            float a = 0.f;
            #pragma unroll 8
            for (int i = 0; i < 256; ++i) a += bv[i] * eL2[i][tid];
            if (half == 0) a += eb1[j0 + tid];
            BC[half * 256 + j0 + tid] = a;
        }
    }
}

// ================================================================ temporal DFT via MFMA, split-k x8 (512 blocks)
__global__ __launch_bounds__(256) void dft_mfma(const float* __restrict__ spikes,
                                                const short* __restrict__ W4P,
                                                float* __restrict__ X64P) {
    __shared__ float red[4][4][64][4];
    int part = blockIdx.x & 7;
    int row0 = (blockIdx.x >> 3) * 16;
    int tid = threadIdx.x, wid = tid >> 6, lane = tid & 63;
    int lrow = lane & 15, lg = lane >> 4;

    f32x4 acc[4];
    #pragma unroll
    for (int n = 0; n < 4; ++n) acc[n] = (f32x4){0.f, 0.f, 0.f, 0.f};

    int row = row0 + lrow;
    const float* sbase = spikes + (size_t)row * 4096;
    #pragma unroll
    for (int kk = 0; kk < 4; ++kk) {
        int k = part * 512 + wid * 128 + kk * 32 + lg * 8;
        const float4* sp = (const float4*)(sbase + k);
        float4 v0 = sp[0], v1 = sp[1];
        U32x4 a;
        a.u[0] = cvtpk(v0.x, v0.y);
        a.u[1] = cvtpk(v0.z, v0.w);
        a.u[2] = cvtpk(v1.x, v1.y);
        a.u[3] = cvtpk(v1.z, v1.w);
        int kkg = part * 16 + wid * 4 + kk;
        #pragma unroll
        for (int n = 0; n < 4; ++n) {
            short8 bfr = *(const short8*)(W4P + ((kkg * 4 + n) * 64 + lane) * 8);
            acc[n] = __builtin_amdgcn_mfma_f32_16x16x32_bf16(a.s8, bfr, acc[n], 0, 0, 0);
        }
    }
    #pragma unroll
    for (int n = 0; n < 4; ++n)
        #pragma unroll
        for (int r = 0; r < 4; ++r) red[wid][n][lane][r] = acc[n][r];
    __syncthreads();
    #pragma unroll
    for (int r = 0; r < 4; ++r) {
        float s = red[0][wid][lane][r] + red[1][wid][lane][r]
                + red[2][wid][lane][r] + red[3][wid][lane][r];
        int orow = row0 + lg * 4 + r;
        X64P[(size_t)part * 65536 + (size_t)orow * 64 + wid * 16 + lrow] = s;
    }
}

// ================================================================ fused node: energy + 4-layer MLP + pspt (M-tile 8, 128 blocks)
__global__ __launch_bounds__(512) void k_node(const float* __restrict__ X64P,
                                              const float* __restrict__ Wr, const float* __restrict__ Wi,
                                              const short* __restrict__ PWP,
                                              const float* __restrict__ pb1, const float* __restrict__ pb2,
                                              const float* __restrict__ nb1, const float* __restrict__ nb2,
                                              const short* __restrict__ WCP, const float* __restrict__ BC,
                                              _Float16* __restrict__ PS16, _Float16* __restrict__ PT16) {
    __shared__ float sx[8][64];
    __shared__ float wri[8192];
    __shared__ short abuf[16 * 128];
    int r0 = blockIdx.x * 8, tid = threadIdx.x;
    int wid = tid >> 6, lane = tid & 63;
    int lrow = lane & 15, lg = lane >> 4;

    {
        int row = tid >> 6, col = tid & 63;
        float v = 0.f;
        #pragma unroll
        for (int p = 0; p < 8; ++p)
            v += X64P[(size_t)p * 65536 + (size_t)(r0 + row) * 64 + col];
        sx[row][col] = v;
    }
    #pragma unroll
    for (int it = 0; it < 16; ++it) {
        int idx = tid + it * 512;
        wri[idx] = (idx < 4096) ? Wr[idx] : Wi[idx - 4096];
    }
    abuf[1024 + tid] = 0;
    abuf[1536 + tid] = 0;
    __syncthreads();

    #pragma unroll
    for (int it = 0; it < 2; ++it) {
        int idx = tid + it * 512;
        int row = idx >> 7, d = idx & 127;
        float acc = 0.f;
        #pragma unroll 8
        for (int k = 0; k < 32; ++k) {
            float a = sx[row][k], b = sx[row][32 + k];
            float wr = wri[k * 128 + d], wi = wri[4096 + k * 128 + d];
            float yr = a * wr - b * wi;
            float yi = a * wi + b * wr;
            acc += sqrtf(yr * yr + yi * yi + 1e-8f);
        }
        abuf[row * 128 + (d ^ ((row & 7) << 3))] = f2bf(acc * (1.0f / 32.0f));
    }
    __syncthreads();

    int asw = (lrow & 7) << 3;
    #pragma unroll 1
    for (int l = 0; l < 4; ++l) {
        f32x4 acc2 = (f32x4){0.f, 0.f, 0.f, 0.f};
        #pragma unroll
        for (int kk = 0; kk < 4; ++kk) {
            short8 a = *(const short8*)(abuf + lrow * 128 + ((kk * 32 + lg * 8) ^ asw));
            short8 b = *(const short8*)(PWP + (((l * 4 + kk) * 8 + wid) * 64 + lane) * 8);
            acc2 = __builtin_amdgcn_mfma_f32_16x16x32_bf16(a, b, acc2, 0, 0, 0);
        }
        __syncthreads();
        const float* bp = (l == 0) ? pb1 : (l == 1) ? pb2 : (l == 2) ? nb1 : nb2;
        bool rl = (l != 1);
        int n = wid * 16 + lrow;
        float bv = bp[n];
        #pragma unroll
        for (int r = 0; r < 4; ++r) {
            int orow = lg * 4 + r;
            float v = acc2[r] + bv;
            if (rl) v = fmaxf(v, 0.f);
            abuf[orow * 128 + (n ^ ((orow & 7) << 3))] = f2bf(v);
        }
        __syncthreads();
    }

    f32x4 acc3[4];
    #pragma unroll
    for (int f = 0; f < 4; ++f) acc3[f] = (f32x4){0.f, 0.f, 0.f, 0.f};
    #pragma unroll
    for (int kk = 0; kk < 4; ++kk) {
        short8 a = *(const short8*)(abuf + lrow * 128 + ((kk * 32 + lg * 8) ^ asw));
        #pragma unroll
        for (int f = 0; f < 4; ++f) {
            short8 b = *(const short8*)(WCP + ((kk * 32 + wid * 4 + f) * 64 + lane) * 8);
            acc3[f] = __builtin_amdgcn_mfma_f32_16x16x32_bf16(a, b, acc3[f], 0, 0, 0);
        }
    }
    if (lg < 2) {
        #pragma unroll
        for (int f = 0; f < 4; ++f) {
            int n = (wid * 4 + f) * 16 + lrow;
            float bv = BC[n];
            _Float16* dst = (n < 256) ? (PS16 + n) : (PT16 + (n - 256));
            #pragma unroll
            for (int r = 0; r < 4; ++r) {
                int row = r0 + lg * 4 + r;
                dst[(size_t)row * 256] = (_Float16)(acc3[f][r] + bv);
            }
        }
    }
}

// ================================================================ edge MLP v10b: hybrid ew2 (hf 0-1 LDS, hf 2-3 L1/global), eb2 folded into acc init
// waves: hh = wid>>2 (h-half), sq = wid&3 (s-quad); 16s x 64t tile; final CC out.
// grid 512 = [b 2][stile 32][ttile 8]; LDS 77.5 KB -> 2 blocks/CU.
__global__ __launch_bounds__(512, 2) void edge_mfma10(
    const _Float16* __restrict__ PS16, const _Float16* __restrict__ PT16,
    const uint4* __restrict__ EW2H4,
    const float* __restrict__ eb2, const float* __restrict__ ew3,
    const float* __restrict__ eb3, unsigned* __restrict__ CC32) {
    __shared__ __align__(16) unsigned ew2s[8192];     // 32 KB: [kk8][hh2][hfl2][lane64] uint4
    __shared__ __align__(16) unsigned pts[8192];      // 32 KB: 64 rows x 32 uint4, XOR-swizzled
    __shared__ __align__(16) unsigned pss[2048];      // 8 KB: 16 rows x 32 uint4
    __shared__ float eb2s[128];
    __shared__ float ew3s[256];
    __shared__ float part[2][4][64][2];               // 4 KB, double-buffered by i&1

    int bidx = blockIdx.x;
    int ttile = bidx & 7;
    int stile = (bidx >> 3) & 31;
    int b = bidx >> 8;
    int s0 = stile * 16, t0 = ttile * 64;
    int tid = threadIdx.x;

    { uint4* dst = (uint4*)ew2s;
      #pragma unroll
      for (int it = 0; it < 4; ++it) {
          int idx = tid + it * 512;                   // 0..2047
          int lane_ = idx & 63;
          int rest = idx >> 6;                        // 0..31
          int hfl = rest & 1, hh_ = (rest >> 1) & 1, kk_ = rest >> 2;
          dst[idx] = EW2H4[(size_t)((kk_ * 8 + hh_ * 4 + hfl) * 64 + lane_)];
      } }
    { const uint4* src = (const uint4*)(PT16 + (size_t)(b * 512 + t0) * 256);
      uint4* dst = (uint4*)pts;
      #pragma unroll
      for (int it = 0; it < 4; ++it) {
          int idx = tid + it * 512;                   // 2048
          int t = idx >> 5, g = idx & 31;
          dst[t * 32 + (g ^ (t & 7))] = src[idx];
      } }
    { const uint4* src = (const uint4*)(PS16 + (size_t)(b * 512 + s0) * 256);
      ((uint4*)pss)[tid] = src[tid]; }
    if (tid < 128) eb2s[tid] = eb2[tid];
    if (tid < 256) ew3s[tid] = ew3[tid];
    __syncthreads();

    int wid = tid >> 6, lane = tid & 63;
    int lrow = lane & 15, lg = lane >> 4;
    int hh = wid >> 2;         // h-half (0: h 0..63, 1: h 64..127)
    int sq = wid & 3;          // s-quad
    float e30 = eb3[0], e31 = eb3[1];
    const uint4* pts4 = (const uint4*)pts;
    const uint4* pss4 = (const uint4*)pss;
    const uint4* ew24 = (const uint4*)ew2s;

    // eb2 fold: preload this wave's 16 bias values (h = hh*64 + hf*16 + lg*4 + r)
    float binit[4][4];
    #pragma unroll
    for (int hf = 0; hf < 4; ++hf)
        #pragma unroll
        for (int r = 0; r < 4; ++r)
            binit[hf][r] = eb2s[hh * 64 + hf * 16 + lg * 4 + r];

    #pragma unroll 1
    for (int i = 0; i < 4; ++i) {
        int s_local = sq * 4 + i;
        int buf = i & 1;

        f32x4 acc[4][4];                  // [hf][tf], init = eb2 bias (added once via MFMA C-in)
        #pragma unroll
        for (int hf = 0; hf < 4; ++hf)
            #pragma unroll
            for (int tf = 0; tf < 4; ++tf)
                #pragma unroll
                for (int r = 0; r < 4; ++r) acc[hf][tf][r] = binit[hf][r];

        #pragma unroll
        for (int kk = 0; kk < 8; ++kk) {
            uint4 pA = pss4[s_local * 32 + kk * 4 + lg];
            uint4 av0 = ew24[(kk * 4 + hh * 2 + 0) * 64 + lane];
            uint4 av1 = ew24[(kk * 4 + hh * 2 + 1) * 64 + lane];
            uint4 av2 = EW2H4[(size_t)((kk * 8 + hh * 4 + 2) * 64 + lane)];
            uint4 av3 = EW2H4[(size_t)((kk * 8 + hh * 4 + 3) * 64 + lane)];
            f16x8 bf[4];
            #pragma unroll
            for (int tf = 0; tf < 4; ++tf) {
                int t = tf * 16 + lrow;
                uint4 v = pts4[t * 32 + ((kk * 4 + lg) ^ (t & 7))];
                U32x4H r;
                r.u[0] = pk_addrelu(v.x, pA.x);
                r.u[1] = pk_addrelu(v.y, pA.y);
                r.u[2] = pk_addrelu(v.z, pA.z);
                r.u[3] = pk_addrelu(v.w, pA.w);
                bf[tf] = r.h8;
            }
            __builtin_amdgcn_s_setprio(1);
            #pragma unroll
            for (int hf = 0; hf < 4; ++hf) {
                U32x4H af;
                uint4 av = (hf == 0) ? av0 : (hf == 1) ? av1 : (hf == 2) ? av2 : av3;
                af.u[0] = av.x; af.u[1] = av.y; af.u[2] = av.z; af.u[3] = av.w;
                #pragma unroll
                for (int tf = 0; tf < 4; ++tf)
                    acc[hf][tf] = __builtin_amdgcn_mfma_f32_16x16x32_f16(af.h8, bf[tf], acc[hf][tf], 0, 0, 0);
            }
            __builtin_amdgcn_s_setprio(0);
        }

        // epilogue: per tf, reduce this wave's 64 h (eb2 already in acc)
        float p0[4], p1[4];
        #pragma unroll
        for (int tf = 0; tf < 4; ++tf) {
            float a0 = 0.f, a1 = 0.f;
            #pragma unroll
            for (int hf = 0; hf < 4; ++hf)
                #pragma unroll
                for (int r = 0; r < 4; ++r) {
                    int h = hh * 64 + hf * 16 + lg * 4 + r;
                    float hv = fmaxf(acc[hf][tf][r], 0.f);
                    a0 += hv * ew3s[2 * h];
                    a1 += hv * ew3s[2 * h + 1];
                }
            a0 += __shfl_xor(a0, 16); a1 += __shfl_xor(a1, 16);
            a0 += __shfl_xor(a0, 32); a1 += __shfl_xor(a1, 32);
            p0[tf] = a0; p1[tf] = a1;
        }
        if (hh == 1 && lg == 0) {
            #pragma unroll
            for (int tf = 0; tf < 4; ++tf) {
                part[buf][sq][tf * 16 + lrow][0] = p0[tf];
                part[buf][sq][tf * 16 + lrow][1] = p1[tf];
            }
        }
        __syncthreads();
        if (hh == 0 && lg == 0) {
            size_t outrow = (size_t)(b * 512 + s0 + s_local) * 512;
            #pragma unroll
            for (int tf = 0; tf < 4; ++tf) {
                int tl = tf * 16 + lrow;
                float t0v = p0[tf] + part[buf][sq][tl][0] + e30;
                float t1v = p1[tf] + part[buf][sq][tl][1] + e31;
                CC32[outrow + t0 + tl] = cvtpk(t0v, t1v);
            }
        }
        // no trailing sync: next iteration writes part[buf^1]
    }
}

// ================================================================ ifft stage 1 (over t): 512 blocks, direct CC reads
__global__ __launch_bounds__(256) void ifft1_mfma(const short* __restrict__ CC,
                                                  const short* __restrict__ F1P,
                                                  short* __restrict__ B2P) {
    __shared__ short st[32 * 64];    // 4 KB
    int bidx = blockIdx.x;           // 512: mt(64) x nt(8)
    int nt = bidx & 7;
    int mt = bidx >> 3;
    int bs0 = mt * 16;
    int b = mt >> 5;
    int kk2 = mt & 31;
    int tid = threadIdx.x, wid = tid >> 6, lane = tid & 63;
    int lrow = lane & 15, lg = lane >> 4;

    f32x4 acc[2];
    acc[0] = (f32x4){0.f, 0.f, 0.f, 0.f};
    acc[1] = (f32x4){0.f, 0.f, 0.f, 0.f};

    const short* arow = CC + (size_t)(bs0 + lrow) * 1024 + lg * 8;
    #pragma unroll 4
    for (int kk = 0; kk < 32; ++kk) {
        short8 a = *(const short8*)(arow + kk * 32);
        #pragma unroll
        for (int f = 0; f < 2; ++f) {
            int nfg = nt * 8 + wid * 2 + f;
            short8 bfr = *(const short8*)(F1P + ((kk * 64 + nfg) * 64 + lane) * 8);
            acc[f] = __builtin_amdgcn_mfma_f32_16x16x32_bf16(a, bfr, acc[f], 0, 0, 0);
        }
    }
    #pragma unroll
    for (int f = 0; f < 2; ++f)
        #pragma unroll
        for (int r = 0; r < 4; ++r) {
            int n_local = (wid * 2 + f) * 16 + lrow;    // 0..127
            int lq = n_local >> 1, d = n_local & 1;     // lq 0..63
            int lk = (lg * 4 + r) * 2 + d;              // 0..31
            st[lk * 64 + lq] = f2bf(acc[f][r]);
        }
    __syncthreads();
    {
        int f2 = wid;                                   // 0..3
        int nf2 = nt * 4 + f2;                          // 0..31
        short8 v;
        #pragma unroll
        for (int j = 0; j < 8; ++j)
            v[j] = st[((lane >> 4) * 8 + j) * 64 + f2 * 16 + (lane & 15)];
        *(short8*)(B2P + (size_t)b * 524288 + ((size_t)(kk2 * 32 + nf2) * 64 + lane) * 8) = v;
    }
}

// ================================================================ ifft stage 2 (over s) + scale/sigmoid: 512 blocks
__global__ __launch_bounds__(256) void ifft2_mfma(const short* __restrict__ B2P,
                                                  const short* __restrict__ F2,
                                                  const float* __restrict__ alpha, const float* __restrict__ beta,
                                                  float* __restrict__ out) {
    int bidx = blockIdx.x;           // 512: pt(32) x qt(8) x b(2)
    int pt_ = bidx & 31;
    int qt = (bidx >> 5) & 7;
    int b = bidx >> 8;
    int p0 = pt_ * 16;
    int tid = threadIdx.x, wid = tid >> 6, lane = tid & 63;
    int lrow = lane & 15, lg = lane >> 4;

    f32x4 acc = (f32x4){0.f, 0.f, 0.f, 0.f};

    const short* arow = F2 + (size_t)(p0 + lrow) * 1024 + lg * 8;
    const short* bbase = B2P + (size_t)b * 524288;
    int nfg = qt * 4 + wid;
    #pragma unroll 4
    for (int kk = 0; kk < 32; ++kk) {
        short8 a = *(const short8*)(arow + kk * 32);
        short8 bfr = *(const short8*)(bbase + ((size_t)(kk * 32 + nfg) * 64 + lane) * 8);
        acc = __builtin_amdgcn_mfma_f32_16x16x32_bf16(a, bfr, acc, 0, 0, 0);
    }
    float al = alpha[0], be = beta[0];
    const float scale = 1.0f / (512.0f * 512.0f);
    #pragma unroll
    for (int r = 0; r < 4; ++r) {
        int q = qt * 64 + wid * 16 + lrow;
        int p = p0 + lg * 4 + r;
        float l = al * (acc[r] * scale) + be;
        size_t idx = (size_t)b * 262144 + (size_t)p * 512 + q;
        out[idx] = l;
        out[524288 + idx] = 1.f / (1.f + expf(-l));
    }
}

// ================================================================ launch
extern "C" void kernel_launch(void* const* d_in, const int* in_sizes, int n_in,
                              void* d_out, int out_size, void* d_ws, size_t ws_size,
                              hipStream_t stream) {
    const float* spikes = (const float*)d_in[0];
    const float* Wr  = (const float*)d_in[1];
    const float* Wi  = (const float*)d_in[2];
    const float* pw1 = (const float*)d_in[3];
    const float* pb1 = (const float*)d_in[4];
    const float* pw2 = (const float*)d_in[5];
    const float* pb2 = (const float*)d_in[6];
    const float* nw1 = (const float*)d_in[7];
    const float* nb1 = (const float*)d_in[8];
    const float* nw2 = (const float*)d_in[9];
    const float* nb2 = (const float*)d_in[10];
    const float* sw  = (const float*)d_in[11];
    const float* sb  = (const float*)d_in[12];
    const float* tw_ = (const float*)d_in[13];
    const float* tb  = (const float*)d_in[14];
    const float* ew1 = (const float*)d_in[15];
    const float* eb1 = (const float*)d_in[16];
    const float* ew2 = (const float*)d_in[17];
    const float* eb2 = (const float*)d_in[18];
    const float* ew3 = (const float*)d_in[19];
    const float* eb3 = (const float*)d_in[20];
    const float* alpha = (const float*)d_in[21];
    const float* beta  = (const float*)d_in[22];
    float* out = (float*)d_out;
    float* ws  = (float*)d_ws;

    // region layout (floats):
    unsigned* CC    = (unsigned*)(ws + 0);        // [0, 524288): final CC (2 MB), overlays X64P
    float*    X64P  = ws + 0;                     // 8*65536 = 524288 f (dead after k_node)
    short*    WCP   = (short*)(ws + 524288);      // 65536 sh = 32768 f (dead after k_node)
    float*    BC    = ws + 557056;                // 512 f (dead after k_node)
    _Float16* PS16  = (_Float16*)(ws + 1048576);  // 131072 f (dead after edge)
    _Float16* PT16  = (_Float16*)(ws + 1179648);  // 131072 f (dead after edge)
    short*    B2P   = (short*)(ws + 1048576);     // 524288 f region [1048576, 1572864), overlays PS/PT
    _Float16* EW2H  = (_Float16*)(ws + 1572864);  // 16384 f
    short*    W4P   = (short*)(ws + 1589248);     // 131072 f
    short*    F1P   = (short*)(ws + 1720320);     // 524288 f
    short*    F2    = (short*)(ws + 2244608);     // 262144 f
    short*    PWP   = (short*)(ws + 2506752);     // 32768 f -> total 2539520 f (10.16 MB)

    setup_kernel<<<504, 256, 0, stream>>>(ew2, pw1, pw2, nw1, nw2, sw, tw_, sb, tb, ew1, eb1,
                                          W4P, F1P, F2, EW2H, PWP, WCP, BC);
    dft_mfma<<<512, 256, 0, stream>>>(spikes, W4P, X64P);
    k_node<<<128, 512, 0, stream>>>(X64P, Wr, Wi, PWP, pb1, pb2, nb1, nb2, WCP, BC, PS16, PT16);
    edge_mfma10<<<512, 512, 0, stream>>>(PS16, PT16, (const uint4*)EW2H, eb2, ew3, eb3, CC);
    ifft1_mfma<<<512, 256, 0, stream>>>((const short*)CC, F1P, B2P);
    ifft2_mfma<<<512, 256, 0, stream>>>(B2P, F2, alpha, beta, out);
}

// Round 22
// 105.654 us; speedup vs baseline: 1.0099x; 1.0099x over previous
//
#include <hip/hip_runtime.h>
#include <hip/hip_bf16.h>
#include <math.h>

typedef __attribute__((ext_vector_type(8))) short short8;
typedef __attribute__((ext_vector_type(8))) _Float16 f16x8;
typedef __attribute__((ext_vector_type(4))) float f32x4;

__device__ __forceinline__ short f2bf(float x) {
    union { float f; unsigned u; } v; v.f = x;
    unsigned r = v.u + 0x7fffu + ((v.u >> 16) & 1u);   // RNE
    return (short)(r >> 16);
}
__device__ __forceinline__ unsigned cvtpk(float lo, float hi) {
    unsigned r;
    asm("v_cvt_pk_bf16_f32 %0, %1, %2" : "=v"(r) : "v"(lo), "v"(hi));
    return r;
}
__device__ __forceinline__ unsigned pk_addrelu(unsigned a, unsigned b) {
    unsigned r;
    asm("v_pk_add_f16 %0, %1, %2\n\tv_pk_max_f16 %0, %0, 0"
        : "=v"(r) : "v"(a), "v"(b));
    return r;
}
union U32x4 { unsigned u[4]; short8 s8; };
union U32x4H { unsigned u[4]; f16x8 h8; };
union HPK { _Float16 h2[2]; unsigned u; };

// ================================================================ setup + combine (grid 504), pair-vectorized
// blk 0..63   : W4P   (u<8, 2/thread)
// blk 64..319 : F1P   (u<8, 2/thread, shared lookup)
// blk 320..447: F2    (u<8, 2/thread, shared lookup)
// blk 448..471: EW2H + PWP (u<8, 2/thread)
// blk 472..503: combine (16-col j-tiles, float4 LDS reads)
__global__ __launch_bounds__(256) void setup_kernel(const float* __restrict__ ew2,
                                                    const float* __restrict__ pw1, const float* __restrict__ pw2,
                                                    const float* __restrict__ nw1, const float* __restrict__ nw2,
                                                    const float* __restrict__ sw, const float* __restrict__ tw,
                                                    const float* __restrict__ sb, const float* __restrict__ tb,
                                                    const float* __restrict__ ew1, const float* __restrict__ eb1,
                                                    short* __restrict__ W4P, short* __restrict__ F1P,
                                                    short* __restrict__ F2, _Float16* __restrict__ EW2H,
                                                    short* __restrict__ PWP,
                                                    short* __restrict__ WCP, float* __restrict__ BC) {
    __shared__ float2 tab[4096];
    __shared__ float eL2[256][16];
    int blk = blockIdx.x, tid = threadIdx.x;
    if (blk < 64) {                                    // W4P (64 blocks)
        for (int i = tid; i < 4096; i += 256) {
            float sn, cs; sincospif((float)i * (1.0f / 2048.0f), &sn, &cs);
            tab[i] = make_float2(cs, sn);
        }
        __syncthreads();
        int base = blk * 4096;
        #pragma unroll 4
        for (int u = 0; u < 8; ++u) {
            int i = base + u * 512 + tid * 2;          // even
            int j = i & 7;                             // even
            int lane = (i >> 3) & 63, nf = (i >> 9) & 3, kkg = i >> 11;
            int k = kkg * 32 + (lane >> 4) * 8 + j;
            int n = nf * 16 + (lane & 15);
            int nm = n & 31;
            float2 cs0 = tab[(k * nm) & 4095];
            float2 cs1 = tab[((k + 1) * nm) & 4095];
            float v0 = n < 32 ? cs0.x : -cs0.y;
            float v1 = n < 32 ? cs1.x : -cs1.y;
            *(unsigned*)(W4P + i) = cvtpk(v0, v1);
        }
    } else if (blk < 320) {                            // F1P (256 blocks)
        for (int i = tid; i < 512; i += 256) {
            float sn, cs; sincospif((float)i * (1.0f / 256.0f), &sn, &cs);
            tab[i] = make_float2(cs, sn);
        }
        __syncthreads();
        int base = (blk - 64) * 4096;
        #pragma unroll 4
        for (int u = 0; u < 8; ++u) {
            int ii = base + u * 512 + tid * 2;         // even
            int j = ii & 7;                            // even -> pair (c=0, c=1)
            int lane = (ii >> 3) & 63, nfg = (ii >> 9) & 63, kk = ii >> 15;
            int k2 = kk * 32 + (lane >> 4) * 8 + j;    // even
            int t = k2 >> 1;
            int n = nfg * 16 + (lane & 15);
            int q = n >> 1, d = n & 1;
            float2 cs = tab[(t * q) & 511];
            float v0 = (d == 0) ? cs.x : cs.y;         // c=0
            float v1 = (d == 1) ? cs.x : -cs.y;        // c=1
            *(unsigned*)(F1P + ii) = cvtpk(v0, v1);
        }
    } else if (blk < 448) {                            // F2 (128 blocks)
        for (int i = tid; i < 512; i += 256) {
            float sn, cs; sincospif((float)i * (1.0f / 256.0f), &sn, &cs);
            tab[i] = make_float2(cs, sn);
        }
        __syncthreads();
        int base = (blk - 320) * 4096;
        #pragma unroll 4
        for (int u = 0; u < 8; ++u) {
            int ii = base + u * 512 + tid * 2;         // even
            int p = ii >> 10, k2 = ii & 1023;          // k2 even -> pair (dd=0, dd=1)
            int s = k2 >> 1;
            float2 cs = tab[(p * s) & 511];
            *(unsigned*)(F2 + ii) = cvtpk(cs.x, -cs.y);
        }
    } else if (blk < 472) {                            // EW2H (fp16) + PWP (bf16), 24 blocks
        int base = (blk - 448) * 4096;
        #pragma unroll 4
        for (int u = 0; u < 8; ++u) {
            int ii = base + u * 512 + tid * 2;         // even
            if (ii < 32768) {
                int j = ii & 7;                        // even -> pair (k, k+1)
                int lane = (ii >> 3) & 63, hf = (ii >> 9) & 7, kk = ii >> 12;
                int k = kk * 32 + (lane >> 4) * 8 + j;
                int h = hf * 16 + (lane & 15);
                HPK pk;
                pk.h2[0] = (_Float16)ew2[k * 128 + h];
                pk.h2[1] = (_Float16)ew2[(k + 1) * 128 + h];
                *(unsigned*)(EW2H + ii) = pk.u;
            } else {
                int iw = ii - 32768;                   // even
                int l = iw >> 14;
                int r = iw & 16383;
                int j = r & 7;                         // even -> pair (k, k+1)
                int lane = (r >> 3) & 63, nf = (r >> 9) & 7, kk = r >> 12;
                int k = kk * 32 + (lane >> 4) * 8 + j;
                int n = nf * 16 + (lane & 15);
                const float* W = (l == 0) ? pw1 : (l == 1) ? pw2 : (l == 2) ? nw1 : nw2;
                *(unsigned*)(PWP + iw) = cvtpk(W[k * 128 + n], W[(k + 1) * 128 + n]);
            }
        }
    } else {                                           // combine (32 blocks, 16-col tiles, float4 LDS)
        int blk2 = blk - 472;                          // 0..31
        int half = blk2 >> 4, jt = blk2 & 15, j0 = jt * 16;
        const float* ebase = ew1 + (size_t)half * 256 * 256;
        #pragma unroll
        for (int it = 0; it < 16; ++it) {
            int idx = tid + it * 256;                  // 4096 = 256 rows x 16 cols
            int i = idx >> 4, jj = idx & 15;
            eL2[i][jj] = ebase[(size_t)i * 256 + j0 + jj];
        }
        __syncthreads();
        const float* wp = half ? tw : sw;
        int d = tid >> 1, jh = tid & 1;
        float acc[8];
        #pragma unroll
        for (int x = 0; x < 8; ++x) acc[x] = 0.f;
        #pragma unroll 4
        for (int i = 0; i < 256; ++i) {
            float wv = wp[(size_t)d * 256 + i];
            const float4* e4 = (const float4*)&eL2[i][jh * 8];
            float4 ea = e4[0], eb = e4[1];
            acc[0] += wv * ea.x; acc[1] += wv * ea.y;
            acc[2] += wv * ea.z; acc[3] += wv * ea.w;
            acc[4] += wv * eb.x; acc[5] += wv * eb.y;
            acc[6] += wv * eb.z; acc[7] += wv * eb.w;
        }
        int kk = d >> 5, lg = (d >> 3) & 3, j = d & 7;
        #pragma unroll
        for (int x = 0; x < 8; ++x) {
            int n = half * 256 + j0 + jh * 8 + x;
            int lane = lg * 16 + (n & 15);
            WCP[((kk * 32 + (n >> 4)) * 64 + lane) * 8 + j] = f2bf(acc[x]);
        }
        if (tid < 16) {
            const float* bv = half ? tb : sb;
            float a = 0.f;
            #pragma unroll 8
            for (int i = 0; i < 256; ++i) a += bv[i] * eL2[i][tid];
            if (half == 0) a += eb1[j0 + tid];
            BC[half * 256 + j0 + tid] = a;
        }
    }
}

// ================================================================ temporal DFT via MFMA, split-k x8 (512 blocks)
__global__ __launch_bounds__(256) void dft_mfma(const float* __restrict__ spikes,
                                                const short* __restrict__ W4P,
                                                float* __restrict__ X64P) {
    __shared__ float red[4][4][64][4];
    int part = blockIdx.x & 7;
    int row0 = (blockIdx.x >> 3) * 16;
    int tid = threadIdx.x, wid = tid >> 6, lane = tid & 63;
    int lrow = lane & 15, lg = lane >> 4;

    f32x4 acc[4];
    #pragma unroll
    for (int n = 0; n < 4; ++n) acc[n] = (f32x4){0.f, 0.f, 0.f, 0.f};

    int row = row0 + lrow;
    const float* sbase = spikes + (size_t)row * 4096;
    #pragma unroll
    for (int kk = 0; kk < 4; ++kk) {
        int k = part * 512 + wid * 128 + kk * 32 + lg * 8;
        const float4* sp = (const float4*)(sbase + k);
        float4 v0 = sp[0], v1 = sp[1];
        U32x4 a;
        a.u[0] = cvtpk(v0.x, v0.y);
        a.u[1] = cvtpk(v0.z, v0.w);
        a.u[2] = cvtpk(v1.x, v1.y);
        a.u[3] = cvtpk(v1.z, v1.w);
        int kkg = part * 16 + wid * 4 + kk;
        #pragma unroll
        for (int n = 0; n < 4; ++n) {
            short8 bfr = *(const short8*)(W4P + ((kkg * 4 + n) * 64 + lane) * 8);
            acc[n] = __builtin_amdgcn_mfma_f32_16x16x32_bf16(a.s8, bfr, acc[n], 0, 0, 0);
        }
    }
    #pragma unroll
    for (int n = 0; n < 4; ++n)
        #pragma unroll
        for (int r = 0; r < 4; ++r) red[wid][n][lane][r] = acc[n][r];
    __syncthreads();
    #pragma unroll
    for (int r = 0; r < 4; ++r) {
        float s = red[0][wid][lane][r] + red[1][wid][lane][r]
                + red[2][wid][lane][r] + red[3][wid][lane][r];
        int orow = row0 + lg * 4 + r;
        X64P[(size_t)part * 65536 + (size_t)orow * 64 + wid * 16 + lrow] = s;
    }
}

// ================================================================ fused node: energy + 4-layer MLP + pspt (M-tile 8, 128 blocks)
__global__ __launch_bounds__(512) void k_node(const float* __restrict__ X64P,
                                              const float* __restrict__ Wr, const float* __restrict__ Wi,
                                              const short* __restrict__ PWP,
                                              const float* __restrict__ pb1, const float* __restrict__ pb2,
                                              const float* __restrict__ nb1, const float* __restrict__ nb2,
                                              const short* __restrict__ WCP, const float* __restrict__ BC,
                                              _Float16* __restrict__ PS16, _Float16* __restrict__ PT16) {
    __shared__ float sx[8][64];
    __shared__ float wri[8192];
    __shared__ short abuf[16 * 128];
    int r0 = blockIdx.x * 8, tid = threadIdx.x;
    int wid = tid >> 6, lane = tid & 63;
    int lrow = lane & 15, lg = lane >> 4;

    {
        int row = tid >> 6, col = tid & 63;
        float v = 0.f;
        #pragma unroll
        for (int p = 0; p < 8; ++p)
            v += X64P[(size_t)p * 65536 + (size_t)(r0 + row) * 64 + col];
        sx[row][col] = v;
    }
    #pragma unroll
    for (int it = 0; it < 16; ++it) {
        int idx = tid + it * 512;
        wri[idx] = (idx < 4096) ? Wr[idx] : Wi[idx - 4096];
    }
    abuf[1024 + tid] = 0;
    abuf[1536 + tid] = 0;
    __syncthreads();

    #pragma unroll
    for (int it = 0; it < 2; ++it) {
        int idx = tid + it * 512;
        int row = idx >> 7, d = idx & 127;
        float acc = 0.f;
        #pragma unroll 8
        for (int k = 0; k < 32; ++k) {
            float a = sx[row][k], b = sx[row][32 + k];
            float wr = wri[k * 128 + d], wi = wri[4096 + k * 128 + d];
            float yr = a * wr - b * wi;
            float yi = a * wi + b * wr;
            acc += sqrtf(yr * yr + yi * yi + 1e-8f);
        }
        abuf[row * 128 + (d ^ ((row & 7) << 3))] = f2bf(acc * (1.0f / 32.0f));
    }
    __syncthreads();

    int asw = (lrow & 7) << 3;
    #pragma unroll 1
    for (int l = 0; l < 4; ++l) {
        f32x4 acc2 = (f32x4){0.f, 0.f, 0.f, 0.f};
        #pragma unroll
        for (int kk = 0; kk < 4; ++kk) {
            short8 a = *(const short8*)(abuf + lrow * 128 + ((kk * 32 + lg * 8) ^ asw));
            short8 b = *(const short8*)(PWP + (((l * 4 + kk) * 8 + wid) * 64 + lane) * 8);
            acc2 = __builtin_amdgcn_mfma_f32_16x16x32_bf16(a, b, acc2, 0, 0, 0);
        }
        __syncthreads();
        const float* bp = (l == 0) ? pb1 : (l == 1) ? pb2 : (l == 2) ? nb1 : nb2;
        bool rl = (l != 1);
        int n = wid * 16 + lrow;
        float bv = bp[n];
        #pragma unroll
        for (int r = 0; r < 4; ++r) {
            int orow = lg * 4 + r;
            float v = acc2[r] + bv;
            if (rl) v = fmaxf(v, 0.f);
            abuf[orow * 128 + (n ^ ((orow & 7) << 3))] = f2bf(v);
        }
        __syncthreads();
    }

    f32x4 acc3[4];
    #pragma unroll
    for (int f = 0; f < 4; ++f) acc3[f] = (f32x4){0.f, 0.f, 0.f, 0.f};
    #pragma unroll
    for (int kk = 0; kk < 4; ++kk) {
        short8 a = *(const short8*)(abuf + lrow * 128 + ((kk * 32 + lg * 8) ^ asw));
        #pragma unroll
        for (int f = 0; f < 4; ++f) {
            short8 b = *(const short8*)(WCP + ((kk * 32 + wid * 4 + f) * 64 + lane) * 8);
            acc3[f] = __builtin_amdgcn_mfma_f32_16x16x32_bf16(a, b, acc3[f], 0, 0, 0);
        }
    }
    if (lg < 2) {
        #pragma unroll
        for (int f = 0; f < 4; ++f) {
            int n = (wid * 4 + f) * 16 + lrow;
            float bv = BC[n];
            _Float16* dst = (n < 256) ? (PS16 + n) : (PT16 + (n - 256));
            #pragma unroll
            for (int r = 0; r < 4; ++r) {
                int row = r0 + lg * 4 + r;
                dst[(size_t)row * 256] = (_Float16)(acc3[f][r] + bv);
            }
        }
    }
}

// ================================================================ edge MLP v10b: hybrid ew2 (hf 0-1 LDS, hf 2-3 L1/global), eb2 folded into acc init
// waves: hh = wid>>2 (h-half), sq = wid&3 (s-quad); 16s x 64t tile; final CC out.
// grid 512 = [b 2][stile 32][ttile 8]; LDS 77.5 KB -> 2 blocks/CU.
__global__ __launch_bounds__(512, 2) void edge_mfma10(
    const _Float16* __restrict__ PS16, const _Float16* __restrict__ PT16,
    const uint4* __restrict__ EW2H4,
    const float* __restrict__ eb2, const float* __restrict__ ew3,
    const float* __restrict__ eb3, unsigned* __restrict__ CC32) {
    __shared__ __align__(16) unsigned ew2s[8192];     // 32 KB: [kk8][hh2][hfl2][lane64] uint4
    __shared__ __align__(16) unsigned pts[8192];      // 32 KB: 64 rows x 32 uint4, XOR-swizzled
    __shared__ __align__(16) unsigned pss[2048];      // 8 KB: 16 rows x 32 uint4
    __shared__ float eb2s[128];
    __shared__ float ew3s[256];
    __shared__ float part[2][4][64][2];               // 4 KB, double-buffered by i&1

    int bidx = blockIdx.x;
    int ttile = bidx & 7;
    int stile = (bidx >> 3) & 31;
    int b = bidx >> 8;
    int s0 = stile * 16, t0 = ttile * 64;
    int tid = threadIdx.x;

    { uint4* dst = (uint4*)ew2s;
      #pragma unroll
      for (int it = 0; it < 4; ++it) {
          int idx = tid + it * 512;                   // 0..2047
          int lane_ = idx & 63;
          int rest = idx >> 6;                        // 0..31
          int hfl = rest & 1, hh_ = (rest >> 1) & 1, kk_ = rest >> 2;
          dst[idx] = EW2H4[(size_t)((kk_ * 8 + hh_ * 4 + hfl) * 64 + lane_)];
      } }
    { const uint4* src = (const uint4*)(PT16 + (size_t)(b * 512 + t0) * 256);
      uint4* dst = (uint4*)pts;
      #pragma unroll
      for (int it = 0; it < 4; ++it) {
          int idx = tid + it * 512;                   // 2048
          int t = idx >> 5, g = idx & 31;
          dst[t * 32 + (g ^ (t & 7))] = src[idx];
      } }
    { const uint4* src = (const uint4*)(PS16 + (size_t)(b * 512 + s0) * 256);
      ((uint4*)pss)[tid] = src[tid]; }
    if (tid < 128) eb2s[tid] = eb2[tid];
    if (tid < 256) ew3s[tid] = ew3[tid];
    __syncthreads();

    int wid = tid >> 6, lane = tid & 63;
    int lrow = lane & 15, lg = lane >> 4;
    int hh = wid >> 2;         // h-half (0: h 0..63, 1: h 64..127)
    int sq = wid & 3;          // s-quad
    float e30 = eb3[0], e31 = eb3[1];
    const uint4* pts4 = (const uint4*)pts;
    const uint4* pss4 = (const uint4*)pss;
    const uint4* ew24 = (const uint4*)ew2s;

    // eb2 fold: preload this wave's 16 bias values (h = hh*64 + hf*16 + lg*4 + r)
    float binit[4][4];
    #pragma unroll
    for (int hf = 0; hf < 4; ++hf)
        #pragma unroll
        for (int r = 0; r < 4; ++r)
            binit[hf][r] = eb2s[hh * 64 + hf * 16 + lg * 4 + r];

    #pragma unroll 1
    for (int i = 0; i < 4; ++i) {
        int s_local = sq * 4 + i;
        int buf = i & 1;

        f32x4 acc[4][4];                  // [hf][tf], init = eb2 bias (added once via MFMA C-in)
        #pragma unroll
        for (int hf = 0; hf < 4; ++hf)
            #pragma unroll
            for (int tf = 0; tf < 4; ++tf)
                #pragma unroll
                for (int r = 0; r < 4; ++r) acc[hf][tf][r] = binit[hf][r];

        #pragma unroll
        for (int kk = 0; kk < 8; ++kk) {
            uint4 pA = pss4[s_local * 32 + kk * 4 + lg];
            uint4 av0 = ew24[(kk * 4 + hh * 2 + 0) * 64 + lane];
            uint4 av1 = ew24[(kk * 4 + hh * 2 + 1) * 64 + lane];
            uint4 av2 = EW2H4[(size_t)((kk * 8 + hh * 4 + 2) * 64 + lane)];
            uint4 av3 = EW2H4[(size_t)((kk * 8 + hh * 4 + 3) * 64 + lane)];
            f16x8 bf[4];
            #pragma unroll
            for (int tf = 0; tf < 4; ++tf) {
                int t = tf * 16 + lrow;
                uint4 v = pts4[t * 32 + ((kk * 4 + lg) ^ (t & 7))];
                U32x4H r;
                r.u[0] = pk_addrelu(v.x, pA.x);
                r.u[1] = pk_addrelu(v.y, pA.y);
                r.u[2] = pk_addrelu(v.z, pA.z);
                r.u[3] = pk_addrelu(v.w, pA.w);
                bf[tf] = r.h8;
            }
            __builtin_amdgcn_s_setprio(1);
            #pragma unroll
            for (int hf = 0; hf < 4; ++hf) {
                U32x4H af;
                uint4 av = (hf == 0) ? av0 : (hf == 1) ? av1 : (hf == 2) ? av2 : av3;
                af.u[0] = av.x; af.u[1] = av.y; af.u[2] = av.z; af.u[3] = av.w;
                #pragma unroll
                for (int tf = 0; tf < 4; ++tf)
                    acc[hf][tf] = __builtin_amdgcn_mfma_f32_16x16x32_f16(af.h8, bf[tf], acc[hf][tf], 0, 0, 0);
            }
            __builtin_amdgcn_s_setprio(0);
        }

        // epilogue: per tf, reduce this wave's 64 h (eb2 already in acc)
        float p0[4], p1[4];
        #pragma unroll
        for (int tf = 0; tf < 4; ++tf) {
            float a0 = 0.f, a1 = 0.f;
            #pragma unroll
            for (int hf = 0; hf < 4; ++hf)
                #pragma unroll
                for (int r = 0; r < 4; ++r) {
                    int h = hh * 64 + hf * 16 + lg * 4 + r;
                    float hv = fmaxf(acc[hf][tf][r], 0.f);
                    a0 += hv * ew3s[2 * h];
                    a1 += hv * ew3s[2 * h + 1];
                }
            a0 += __shfl_xor(a0, 16); a1 += __shfl_xor(a1, 16);
            a0 += __shfl_xor(a0, 32); a1 += __shfl_xor(a1, 32);
            p0[tf] = a0; p1[tf] = a1;
        }
        if (hh == 1 && lg == 0) {
            #pragma unroll
            for (int tf = 0; tf < 4; ++tf) {
                part[buf][sq][tf * 16 + lrow][0] = p0[tf];
                part[buf][sq][tf * 16 + lrow][1] = p1[tf];
            }
        }
        __syncthreads();
        if (hh == 0 && lg == 0) {
            size_t outrow = (size_t)(b * 512 + s0 + s_local) * 512;
            #pragma unroll
            for (int tf = 0; tf < 4; ++tf) {
                int tl = tf * 16 + lrow;
                float t0v = p0[tf] + part[buf][sq][tl][0] + e30;
                float t1v = p1[tf] + part[buf][sq][tl][1] + e31;
                CC32[outrow + t0 + tl] = cvtpk(t0v, t1v);
            }
        }
        // no trailing sync: next iteration writes part[buf^1]
    }
}

// ================================================================ ifft stage 1 (over t): 512 blocks, direct CC reads
__global__ __launch_bounds__(256) void ifft1_mfma(const short* __restrict__ CC,
                                                  const short* __restrict__ F1P,
                                                  short* __restrict__ B2P) {
    __shared__ short st[32 * 64];    // 4 KB
    int bidx = blockIdx.x;           // 512: mt(64) x nt(8)
    int nt = bidx & 7;
    int mt = bidx >> 3;
    int bs0 = mt * 16;
    int b = mt >> 5;
    int kk2 = mt & 31;
    int tid = threadIdx.x, wid = tid >> 6, lane = tid & 63;
    int lrow = lane & 15, lg = lane >> 4;

    f32x4 acc[2];
    acc[0] = (f32x4){0.f, 0.f, 0.f, 0.f};
    acc[1] = (f32x4){0.f, 0.f, 0.f, 0.f};

    const short* arow = CC + (size_t)(bs0 + lrow) * 1024 + lg * 8;
    #pragma unroll 4
    for (int kk = 0; kk < 32; ++kk) {
        short8 a = *(const short8*)(arow + kk * 32);
        #pragma unroll
        for (int f = 0; f < 2; ++f) {
            int nfg = nt * 8 + wid * 2 + f;
            short8 bfr = *(const short8*)(F1P + ((kk * 64 + nfg) * 64 + lane) * 8);
            acc[f] = __builtin_amdgcn_mfma_f32_16x16x32_bf16(a, bfr, acc[f], 0, 0, 0);
        }
    }
    #pragma unroll
    for (int f = 0; f < 2; ++f)
        #pragma unroll
        for (int r = 0; r < 4; ++r) {
            int n_local = (wid * 2 + f) * 16 + lrow;    // 0..127
            int lq = n_local >> 1, d = n_local & 1;     // lq 0..63
            int lk = (lg * 4 + r) * 2 + d;              // 0..31
            st[lk * 64 + lq] = f2bf(acc[f][r]);
        }
    __syncthreads();
    {
        int f2 = wid;                                   // 0..3
        int nf2 = nt * 4 + f2;                          // 0..31
        short8 v;
        #pragma unroll
        for (int j = 0; j < 8; ++j)
            v[j] = st[((lane >> 4) * 8 + j) * 64 + f2 * 16 + (lane & 15)];
        *(short8*)(B2P + (size_t)b * 524288 + ((size_t)(kk2 * 32 + nf2) * 64 + lane) * 8) = v;
    }
}

// ================================================================ ifft stage 2 (over s) + scale/sigmoid: 512 blocks
__global__ __launch_bounds__(256) void ifft2_mfma(const short* __restrict__ B2P,
                                                  const short* __restrict__ F2,
                                                  const float* __restrict__ alpha, const float* __restrict__ beta,
                                                  float* __restrict__ out) {
    int bidx = blockIdx.x;           // 512: pt(32) x qt(8) x b(2)
    int pt_ = bidx & 31;
    int qt = (bidx >> 5) & 7;
    int b = bidx >> 8;
    int p0 = pt_ * 16;
    int tid = threadIdx.x, wid = tid >> 6, lane = tid & 63;
    int lrow = lane & 15, lg = lane >> 4;

    f32x4 acc = (f32x4){0.f, 0.f, 0.f, 0.f};

    const short* arow = F2 + (size_t)(p0 + lrow) * 1024 + lg * 8;
    const short* bbase = B2P + (size_t)b * 524288;
    int nfg = qt * 4 + wid;
    #pragma unroll 4
    for (int kk = 0; kk < 32; ++kk) {
        short8 a = *(const short8*)(arow + kk * 32);
        short8 bfr = *(const short8*)(bbase + ((size_t)(kk * 32 + nfg) * 64 + lane) * 8);
        acc = __builtin_amdgcn_mfma_f32_16x16x32_bf16(a, bfr, acc, 0, 0, 0);
    }
    float al = alpha[0], be = beta[0];
    const float scale = 1.0f / (512.0f * 512.0f);
    #pragma unroll
    for (int r = 0; r < 4; ++r) {
        int q = qt * 64 + wid * 16 + lrow;
        int p = p0 + lg * 4 + r;
        float l = al * (acc[r] * scale) + be;
        size_t idx = (size_t)b * 262144 + (size_t)p * 512 + q;
        out[idx] = l;
        out[524288 + idx] = 1.f / (1.f + expf(-l));
    }
}

// ================================================================ launch
extern "C" void kernel_launch(void* const* d_in, const int* in_sizes, int n_in,
                              void* d_out, int out_size, void* d_ws, size_t ws_size,
                              hipStream_t stream) {
    const float* spikes = (const float*)d_in[0];
    const float* Wr  = (const float*)d_in[1];
    const float* Wi  = (const float*)d_in[2];
    const float* pw1 = (const float*)d_in[3];
    const float* pb1 = (const float*)d_in[4];
    const float* pw2 = (const float*)d_in[5];
    const float* pb2 = (const float*)d_in[6];
    const float* nw1 = (const float*)d_in[7];
    const float* nb1 = (const float*)d_in[8];
    const float* nw2 = (const float*)d_in[9];
    const float* nb2 = (const float*)d_in[10];
    const float* sw  = (const float*)d_in[11];
    const float* sb  = (const float*)d_in[12];
    const float* tw_ = (const float*)d_in[13];
    const float* tb  = (const float*)d_in[14];
    const float* ew1 = (const float*)d_in[15];
    const float* eb1 = (const float*)d_in[16];
    const float* ew2 = (const float*)d_in[17];
    const float* eb2 = (const float*)d_in[18];
    const float* ew3 = (const float*)d_in[19];
    const float* eb3 = (const float*)d_in[20];
    const float* alpha = (const float*)d_in[21];
    const float* beta  = (const float*)d_in[22];
    float* out = (float*)d_out;
    float* ws  = (float*)d_ws;

    // region layout (floats):
    unsigned* CC    = (unsigned*)(ws + 0);        // [0, 524288): final CC (2 MB), overlays X64P
    float*    X64P  = ws + 0;                     // 8*65536 = 524288 f (dead after k_node)
    short*    WCP   = (short*)(ws + 524288);      // 65536 sh = 32768 f (dead after k_node)
    float*    BC    = ws + 557056;                // 512 f (dead after k_node)
    _Float16* PS16  = (_Float16*)(ws + 1048576);  // 131072 f (dead after edge)
    _Float16* PT16  = (_Float16*)(ws + 1179648);  // 131072 f (dead after edge)
    short*    B2P   = (short*)(ws + 1048576);     // 524288 f region [1048576, 1572864), overlays PS/PT
    _Float16* EW2H  = (_Float16*)(ws + 1572864);  // 16384 f
    short*    W4P   = (short*)(ws + 1589248);     // 131072 f
    short*    F1P   = (short*)(ws + 1720320);     // 524288 f
    short*    F2    = (short*)(ws + 2244608);     // 262144 f
    short*    PWP   = (short*)(ws + 2506752);     // 32768 f -> total 2539520 f (10.16 MB)

    setup_kernel<<<504, 256, 0, stream>>>(ew2, pw1, pw2, nw1, nw2, sw, tw_, sb, tb, ew1, eb1,
                                          W4P, F1P, F2, EW2H, PWP, WCP, BC);
    dft_mfma<<<512, 256, 0, stream>>>(spikes, W4P, X64P);
    k_node<<<128, 512, 0, stream>>>(X64P, Wr, Wi, PWP, pb1, pb2, nb1, nb2, WCP, BC, PS16, PT16);
    edge_mfma10<<<512, 512, 0, stream>>>(PS16, PT16, (const uint4*)EW2H, eb2, ew3, eb3, CC);
    ifft1_mfma<<<512, 256, 0, stream>>>((const short*)CC, F1P, B2P);
    ifft2_mfma<<<512, 256, 0, stream>>>(B2P, F2, alpha, beta, out);
}

// Round 23
// 105.446 us; speedup vs baseline: 1.0119x; 1.0020x over previous
//
#include <hip/hip_runtime.h>
#include <hip/hip_bf16.h>
#include <math.h>

typedef __attribute__((ext_vector_type(8))) short short8;
typedef __attribute__((ext_vector_type(8))) _Float16 f16x8;
typedef __attribute__((ext_vector_type(4))) float f32x4;

__device__ __forceinline__ short f2bf(float x) {
    union { float f; unsigned u; } v; v.f = x;
    unsigned r = v.u + 0x7fffu + ((v.u >> 16) & 1u);   // RNE
    return (short)(r >> 16);
}
__device__ __forceinline__ unsigned cvtpk(float lo, float hi) {
    unsigned r;
    asm("v_cvt_pk_bf16_f32 %0, %1, %2" : "=v"(r) : "v"(lo), "v"(hi));
    return r;
}
__device__ __forceinline__ unsigned pk_addrelu(unsigned a, unsigned b) {
    unsigned r;
    asm("v_pk_add_f16 %0, %1, %2\n\tv_pk_max_f16 %0, %0, 0"
        : "=v"(r) : "v"(a), "v"(b));
    return r;
}
union U32x4 { unsigned u[4]; short8 s8; };
union U32x4H { unsigned u[4]; f16x8 h8; };
union HPK { _Float16 h2[2]; unsigned u; };

// ================================================================ setup + combine (grid 504), pair-vectorized
// blk 0..63   : W4P   (u<8, 2/thread)
// blk 64..319 : F1P   (u<8, 2/thread, shared lookup)
// blk 320..447: F2    (u<8, 2/thread, shared lookup)
// blk 448..471: EW2H + PWP (u<8, 2/thread)
// blk 472..503: combine (16-col j-tiles, float4 LDS reads)
__global__ __launch_bounds__(256) void setup_kernel(const float* __restrict__ ew2,
                                                    const float* __restrict__ pw1, const float* __restrict__ pw2,
                                                    const float* __restrict__ nw1, const float* __restrict__ nw2,
                                                    const float* __restrict__ sw, const float* __restrict__ tw,
                                                    const float* __restrict__ sb, const float* __restrict__ tb,
                                                    const float* __restrict__ ew1, const float* __restrict__ eb1,
                                                    short* __restrict__ W4P, short* __restrict__ F1P,
                                                    short* __restrict__ F2, _Float16* __restrict__ EW2H,
                                                    short* __restrict__ PWP,
                                                    short* __restrict__ WCP, float* __restrict__ BC) {
    __shared__ float2 tab[4096];
    __shared__ float eL2[256][16];
    int blk = blockIdx.x, tid = threadIdx.x;
    if (blk < 64) {                                    // W4P (64 blocks)
        for (int i = tid; i < 4096; i += 256) {
            float sn, cs; sincospif((float)i * (1.0f / 2048.0f), &sn, &cs);
            tab[i] = make_float2(cs, sn);
        }
        __syncthreads();
        int base = blk * 4096;
        #pragma unroll 4
        for (int u = 0; u < 8; ++u) {
            int i = base + u * 512 + tid * 2;          // even
            int j = i & 7;                             // even
            int lane = (i >> 3) & 63, nf = (i >> 9) & 3, kkg = i >> 11;
            int k = kkg * 32 + (lane >> 4) * 8 + j;
            int n = nf * 16 + (lane & 15);
            int nm = n & 31;
            float2 cs0 = tab[(k * nm) & 4095];
            float2 cs1 = tab[((k + 1) * nm) & 4095];
            float v0 = n < 32 ? cs0.x : -cs0.y;
            float v1 = n < 32 ? cs1.x : -cs1.y;
            *(unsigned*)(W4P + i) = cvtpk(v0, v1);
        }
    } else if (blk < 320) {                            // F1P (256 blocks)
        for (int i = tid; i < 512; i += 256) {
            float sn, cs; sincospif((float)i * (1.0f / 256.0f), &sn, &cs);
            tab[i] = make_float2(cs, sn);
        }
        __syncthreads();
        int base = (blk - 64) * 4096;
        #pragma unroll 4
        for (int u = 0; u < 8; ++u) {
            int ii = base + u * 512 + tid * 2;         // even
            int j = ii & 7;                            // even -> pair (c=0, c=1)
            int lane = (ii >> 3) & 63, nfg = (ii >> 9) & 63, kk = ii >> 15;
            int k2 = kk * 32 + (lane >> 4) * 8 + j;    // even
            int t = k2 >> 1;
            int n = nfg * 16 + (lane & 15);
            int q = n >> 1, d = n & 1;
            float2 cs = tab[(t * q) & 511];
            float v0 = (d == 0) ? cs.x : cs.y;         // c=0
            float v1 = (d == 1) ? cs.x : -cs.y;        // c=1
            *(unsigned*)(F1P + ii) = cvtpk(v0, v1);
        }
    } else if (blk < 448) {                            // F2 (128 blocks)
        for (int i = tid; i < 512; i += 256) {
            float sn, cs; sincospif((float)i * (1.0f / 256.0f), &sn, &cs);
            tab[i] = make_float2(cs, sn);
        }
        __syncthreads();
        int base = (blk - 320) * 4096;
        #pragma unroll 4
        for (int u = 0; u < 8; ++u) {
            int ii = base + u * 512 + tid * 2;         // even
            int p = ii >> 10, k2 = ii & 1023;          // k2 even -> pair (dd=0, dd=1)
            int s = k2 >> 1;
            float2 cs = tab[(p * s) & 511];
            *(unsigned*)(F2 + ii) = cvtpk(cs.x, -cs.y);
        }
    } else if (blk < 472) {                            // EW2H (fp16) + PWP (bf16), 24 blocks
        int base = (blk - 448) * 4096;
        #pragma unroll 4
        for (int u = 0; u < 8; ++u) {
            int ii = base + u * 512 + tid * 2;         // even
            if (ii < 32768) {
                int j = ii & 7;                        // even -> pair (k, k+1)
                int lane = (ii >> 3) & 63, hf = (ii >> 9) & 7, kk = ii >> 12;
                int k = kk * 32 + (lane >> 4) * 8 + j;
                int h = hf * 16 + (lane & 15);
                HPK pk;
                pk.h2[0] = (_Float16)ew2[k * 128 + h];
                pk.h2[1] = (_Float16)ew2[(k + 1) * 128 + h];
                *(unsigned*)(EW2H + ii) = pk.u;
            } else {
                int iw = ii - 32768;                   // even
                int l = iw >> 14;
                int r = iw & 16383;
                int j = r & 7;                         // even -> pair (k, k+1)
                int lane = (r >> 3) & 63, nf = (r >> 9) & 7, kk = r >> 12;
                int k = kk * 32 + (lane >> 4) * 8 + j;
                int n = nf * 16 + (lane & 15);
                const float* W = (l == 0) ? pw1 : (l == 1) ? pw2 : (l == 2) ? nw1 : nw2;
                *(unsigned*)(PWP + iw) = cvtpk(W[k * 128 + n], W[(k + 1) * 128 + n]);
            }
        }
    } else {                                           // combine (32 blocks, 16-col tiles, float4 LDS)
        int blk2 = blk - 472;                          // 0..31
        int half = blk2 >> 4, jt = blk2 & 15, j0 = jt * 16;
        const float* ebase = ew1 + (size_t)half * 256 * 256;
        #pragma unroll
        for (int it = 0; it < 16; ++it) {
            int idx = tid + it * 256;                  // 4096 = 256 rows x 16 cols
            int i = idx >> 4, jj = idx & 15;
            eL2[i][jj] = ebase[(size_t)i * 256 + j0 + jj];
        }
        __syncthreads();
        const float* wp = half ? tw : sw;
        int d = tid >> 1, jh = tid & 1;
        float acc[8];
        #pragma unroll
        for (int x = 0; x < 8; ++x) acc[x] = 0.f;
        #pragma unroll 4
        for (int i = 0; i < 256; ++i) {
            float wv = wp[(size_t)d * 256 + i];
            const float4* e4 = (const float4*)&eL2[i][jh * 8];
            float4 ea = e4[0], eb = e4[1];
            acc[0] += wv * ea.x; acc[1] += wv * ea.y;
            acc[2] += wv * ea.z; acc[3] += wv * ea.w;
            acc[4] += wv * eb.x; acc[5] += wv * eb.y;
            acc[6] += wv * eb.z; acc[7] += wv * eb.w;
        }
        int kk = d >> 5, lg = (d >> 3) & 3, j = d & 7;
        #pragma unroll
        for (int x = 0; x < 8; ++x) {
            int n = half * 256 + j0 + jh * 8 + x;
            int lane = lg * 16 + (n & 15);
            WCP[((kk * 32 + (n >> 4)) * 64 + lane) * 8 + j] = f2bf(acc[x]);
        }
        if (tid < 16) {
            const float* bv = half ? tb : sb;
            float a = 0.f;
            #pragma unroll 8
            for (int i = 0; i < 256; ++i) a += bv[i] * eL2[i][tid];
            if (half == 0) a += eb1[j0 + tid];
            BC[half * 256 + j0 + tid] = a;
        }
    }
}

// ================================================================ temporal DFT via MFMA, split-k x8 (512 blocks)
__global__ __launch_bounds__(256) void dft_mfma(const float* __restrict__ spikes,
                                                const short* __restrict__ W4P,
                                                float* __restrict__ X64P) {
    __shared__ float red[4][4][64][4];
    int part = blockIdx.x & 7;
    int row0 = (blockIdx.x >> 3) * 16;
    int tid = threadIdx.x, wid = tid >> 6, lane = tid & 63;
    int lrow = lane & 15, lg = lane >> 4;

    f32x4 acc[4];
    #pragma unroll
    for (int n = 0; n < 4; ++n) acc[n] = (f32x4){0.f, 0.f, 0.f, 0.f};

    int row = row0 + lrow;
    const float* sbase = spikes + (size_t)row * 4096;
    #pragma unroll
    for (int kk = 0; kk < 4; ++kk) {
        int k = part * 512 + wid * 128 + kk * 32 + lg * 8;
        const float4* sp = (const float4*)(sbase + k);
        float4 v0 = sp[0], v1 = sp[1];
        U32x4 a;
        a.u[0] = cvtpk(v0.x, v0.y);
        a.u[1] = cvtpk(v0.z, v0.w);
        a.u[2] = cvtpk(v1.x, v1.y);
        a.u[3] = cvtpk(v1.z, v1.w);
        int kkg = part * 16 + wid * 4 + kk;
        #pragma unroll
        for (int n = 0; n < 4; ++n) {
            short8 bfr = *(const short8*)(W4P + ((kkg * 4 + n) * 64 + lane) * 8);
            acc[n] = __builtin_amdgcn_mfma_f32_16x16x32_bf16(a.s8, bfr, acc[n], 0, 0, 0);
        }
    }
    #pragma unroll
    for (int n = 0; n < 4; ++n)
        #pragma unroll
        for (int r = 0; r < 4; ++r) red[wid][n][lane][r] = acc[n][r];
    __syncthreads();
    #pragma unroll
    for (int r = 0; r < 4; ++r) {
        float s = red[0][wid][lane][r] + red[1][wid][lane][r]
                + red[2][wid][lane][r] + red[3][wid][lane][r];
        int orow = row0 + lg * 4 + r;
        X64P[(size_t)part * 65536 + (size_t)orow * 64 + wid * 16 + lrow] = s;
    }
}

// ================================================================ fused node: energy + 4-layer MLP + pspt (M-tile 8, 128 blocks)
__global__ __launch_bounds__(512) void k_node(const float* __restrict__ X64P,
                                              const float* __restrict__ Wr, const float* __restrict__ Wi,
                                              const short* __restrict__ PWP,
                                              const float* __restrict__ pb1, const float* __restrict__ pb2,
                                              const float* __restrict__ nb1, const float* __restrict__ nb2,
                                              const short* __restrict__ WCP, const float* __restrict__ BC,
                                              _Float16* __restrict__ PS16, _Float16* __restrict__ PT16) {
    __shared__ float sx[8][64];
    __shared__ float wri[8192];
    __shared__ short abuf[16 * 128];
    int r0 = blockIdx.x * 8, tid = threadIdx.x;
    int wid = tid >> 6, lane = tid & 63;
    int lrow = lane & 15, lg = lane >> 4;

    {
        int row = tid >> 6, col = tid & 63;
        float v = 0.f;
        #pragma unroll
        for (int p = 0; p < 8; ++p)
            v += X64P[(size_t)p * 65536 + (size_t)(r0 + row) * 64 + col];
        sx[row][col] = v;
    }
    #pragma unroll
    for (int it = 0; it < 16; ++it) {
        int idx = tid + it * 512;
        wri[idx] = (idx < 4096) ? Wr[idx] : Wi[idx - 4096];
    }
    abuf[1024 + tid] = 0;
    abuf[1536 + tid] = 0;
    __syncthreads();

    #pragma unroll
    for (int it = 0; it < 2; ++it) {
        int idx = tid + it * 512;
        int row = idx >> 7, d = idx & 127;
        float acc = 0.f;
        #pragma unroll 8
        for (int k = 0; k < 32; ++k) {
            float a = sx[row][k], b = sx[row][32 + k];
            float wr = wri[k * 128 + d], wi = wri[4096 + k * 128 + d];
            float yr = a * wr - b * wi;
            float yi = a * wi + b * wr;
            acc += sqrtf(yr * yr + yi * yi + 1e-8f);
        }
        abuf[row * 128 + (d ^ ((row & 7) << 3))] = f2bf(acc * (1.0f / 32.0f));
    }
    __syncthreads();

    int asw = (lrow & 7) << 3;
    #pragma unroll 1
    for (int l = 0; l < 4; ++l) {
        f32x4 acc2 = (f32x4){0.f, 0.f, 0.f, 0.f};
        #pragma unroll
        for (int kk = 0; kk < 4; ++kk) {
            short8 a = *(const short8*)(abuf + lrow * 128 + ((kk * 32 + lg * 8) ^ asw));
            short8 b = *(const short8*)(PWP + (((l * 4 + kk) * 8 + wid) * 64 + lane) * 8);
            acc2 = __builtin_amdgcn_mfma_f32_16x16x32_bf16(a, b, acc2, 0, 0, 0);
        }
        __syncthreads();
        const float* bp = (l == 0) ? pb1 : (l == 1) ? pb2 : (l == 2) ? nb1 : nb2;
        bool rl = (l != 1);
        int n = wid * 16 + lrow;
        float bv = bp[n];
        #pragma unroll
        for (int r = 0; r < 4; ++r) {
            int orow = lg * 4 + r;
            float v = acc2[r] + bv;
            if (rl) v = fmaxf(v, 0.f);
            abuf[orow * 128 + (n ^ ((orow & 7) << 3))] = f2bf(v);
        }
        __syncthreads();
    }

    f32x4 acc3[4];
    #pragma unroll
    for (int f = 0; f < 4; ++f) acc3[f] = (f32x4){0.f, 0.f, 0.f, 0.f};
    #pragma unroll
    for (int kk = 0; kk < 4; ++kk) {
        short8 a = *(const short8*)(abuf + lrow * 128 + ((kk * 32 + lg * 8) ^ asw));
        #pragma unroll
        for (int f = 0; f < 4; ++f) {
            short8 b = *(const short8*)(WCP + ((kk * 32 + wid * 4 + f) * 64 + lane) * 8);
            acc3[f] = __builtin_amdgcn_mfma_f32_16x16x32_bf16(a, b, acc3[f], 0, 0, 0);
        }
    }
    if (lg < 2) {
        #pragma unroll
        for (int f = 0; f < 4; ++f) {
            int n = (wid * 4 + f) * 16 + lrow;
            float bv = BC[n];
            _Float16* dst = (n < 256) ? (PS16 + n) : (PT16 + (n - 256));
            #pragma unroll
            for (int r = 0; r < 4; ++r) {
                int row = r0 + lg * 4 + r;
                dst[(size_t)row * 256] = (_Float16)(acc3[f][r] + bv);
            }
        }
    }
}

// ================================================================ edge MLP v10b: hybrid ew2 (hf 0-1 LDS, hf 2-3 L1/global), eb2 folded into acc init
// waves: hh = wid>>2 (h-half), sq = wid&3 (s-quad); 16s x 64t tile; final CC out.
// grid 512 = [b 2][stile 32][ttile 8]; LDS 77.5 KB -> 2 blocks/CU.
__global__ __launch_bounds__(512, 2) void edge_mfma10(
    const _Float16* __restrict__ PS16, const _Float16* __restrict__ PT16,
    const uint4* __restrict__ EW2H4,
    const float* __restrict__ eb2, const float* __restrict__ ew3,
    const float* __restrict__ eb3, unsigned* __restrict__ CC32) {
    __shared__ __align__(16) unsigned ew2s[8192];     // 32 KB: [kk8][hh2][hfl2][lane64] uint4
    __shared__ __align__(16) unsigned pts[8192];      // 32 KB: 64 rows x 32 uint4, XOR-swizzled
    __shared__ __align__(16) unsigned pss[2048];      // 8 KB: 16 rows x 32 uint4
    __shared__ float eb2s[128];
    __shared__ float ew3s[256];
    __shared__ float part[2][4][64][2];               // 4 KB, double-buffered by i&1

    int bidx = blockIdx.x;
    int ttile = bidx & 7;
    int stile = (bidx >> 3) & 31;
    int b = bidx >> 8;
    int s0 = stile * 16, t0 = ttile * 64;
    int tid = threadIdx.x;

    { uint4* dst = (uint4*)ew2s;
      #pragma unroll
      for (int it = 0; it < 4; ++it) {
          int idx = tid + it * 512;                   // 0..2047
          int lane_ = idx & 63;
          int rest = idx >> 6;                        // 0..31
          int hfl = rest & 1, hh_ = (rest >> 1) & 1, kk_ = rest >> 2;
          dst[idx] = EW2H4[(size_t)((kk_ * 8 + hh_ * 4 + hfl) * 64 + lane_)];
      } }
    { const uint4* src = (const uint4*)(PT16 + (size_t)(b * 512 + t0) * 256);
      uint4* dst = (uint4*)pts;
      #pragma unroll
      for (int it = 0; it < 4; ++it) {
          int idx = tid + it * 512;                   // 2048
          int t = idx >> 5, g = idx & 31;
          dst[t * 32 + (g ^ (t & 7))] = src[idx];
      } }
    { const uint4* src = (const uint4*)(PS16 + (size_t)(b * 512 + s0) * 256);
      ((uint4*)pss)[tid] = src[tid]; }
    if (tid < 128) eb2s[tid] = eb2[tid];
    if (tid < 256) ew3s[tid] = ew3[tid];
    __syncthreads();

    int wid = tid >> 6, lane = tid & 63;
    int lrow = lane & 15, lg = lane >> 4;
    int hh = wid >> 2;         // h-half (0: h 0..63, 1: h 64..127)
    int sq = wid & 3;          // s-quad
    float e30 = eb3[0], e31 = eb3[1];
    const uint4* pts4 = (const uint4*)pts;
    const uint4* pss4 = (const uint4*)pss;
    const uint4* ew24 = (const uint4*)ew2s;

    // eb2 fold: preload this wave's 16 bias values (h = hh*64 + hf*16 + lg*4 + r)
    float binit[4][4];
    #pragma unroll
    for (int hf = 0; hf < 4; ++hf)
        #pragma unroll
        for (int r = 0; r < 4; ++r)
            binit[hf][r] = eb2s[hh * 64 + hf * 16 + lg * 4 + r];

    #pragma unroll 1
    for (int i = 0; i < 4; ++i) {
        int s_local = sq * 4 + i;
        int buf = i & 1;

        f32x4 acc[4][4];                  // [hf][tf], init = eb2 bias (added once via MFMA C-in)
        #pragma unroll
        for (int hf = 0; hf < 4; ++hf)
            #pragma unroll
            for (int tf = 0; tf < 4; ++tf)
                #pragma unroll
                for (int r = 0; r < 4; ++r) acc[hf][tf][r] = binit[hf][r];

        #pragma unroll
        for (int kk = 0; kk < 8; ++kk) {
            uint4 pA = pss4[s_local * 32 + kk * 4 + lg];
            uint4 av0 = ew24[(kk * 4 + hh * 2 + 0) * 64 + lane];
            uint4 av1 = ew24[(kk * 4 + hh * 2 + 1) * 64 + lane];
            uint4 av2 = EW2H4[(size_t)((kk * 8 + hh * 4 + 2) * 64 + lane)];
            uint4 av3 = EW2H4[(size_t)((kk * 8 + hh * 4 + 3) * 64 + lane)];
            f16x8 bf[4];
            #pragma unroll
            for (int tf = 0; tf < 4; ++tf) {
                int t = tf * 16 + lrow;
                uint4 v = pts4[t * 32 + ((kk * 4 + lg) ^ (t & 7))];
                U32x4H r;
                r.u[0] = pk_addrelu(v.x, pA.x);
                r.u[1] = pk_addrelu(v.y, pA.y);
                r.u[2] = pk_addrelu(v.z, pA.z);
                r.u[3] = pk_addrelu(v.w, pA.w);
                bf[tf] = r.h8;
            }
            __builtin_amdgcn_s_setprio(1);
            #pragma unroll
            for (int hf = 0; hf < 4; ++hf) {
                U32x4H af;
                uint4 av = (hf == 0) ? av0 : (hf == 1) ? av1 : (hf == 2) ? av2 : av3;
                af.u[0] = av.x; af.u[1] = av.y; af.u[2] = av.z; af.u[3] = av.w;
                #pragma unroll
                for (int tf = 0; tf < 4; ++tf)
                    acc[hf][tf] = __builtin_amdgcn_mfma_f32_16x16x32_f16(af.h8, bf[tf], acc[hf][tf], 0, 0, 0);
            }
            __builtin_amdgcn_s_setprio(0);
        }

        // epilogue: per tf, reduce this wave's 64 h (eb2 already in acc)
        float p0[4], p1[4];
        #pragma unroll
        for (int tf = 0; tf < 4; ++tf) {
            float a0 = 0.f, a1 = 0.f;
            #pragma unroll
            for (int hf = 0; hf < 4; ++hf)
                #pragma unroll
                for (int r = 0; r < 4; ++r) {
                    int h = hh * 64 + hf * 16 + lg * 4 + r;
                    float hv = fmaxf(acc[hf][tf][r], 0.f);
                    a0 += hv * ew3s[2 * h];
                    a1 += hv * ew3s[2 * h + 1];
                }
            a0 += __shfl_xor(a0, 16); a1 += __shfl_xor(a1, 16);
            a0 += __shfl_xor(a0, 32); a1 += __shfl_xor(a1, 32);
            p0[tf] = a0; p1[tf] = a1;
        }
        if (hh == 1 && lg == 0) {
            #pragma unroll
            for (int tf = 0; tf < 4; ++tf) {
                part[buf][sq][tf * 16 + lrow][0] = p0[tf];
                part[buf][sq][tf * 16 + lrow][1] = p1[tf];
            }
        }
        __syncthreads();
        if (hh == 0 && lg == 0) {
            size_t outrow = (size_t)(b * 512 + s0 + s_local) * 512;
            #pragma unroll
            for (int tf = 0; tf < 4; ++tf) {
                int tl = tf * 16 + lrow;
                float t0v = p0[tf] + part[buf][sq][tl][0] + e30;
                float t1v = p1[tf] + part[buf][sq][tl][1] + e31;
                CC32[outrow + t0 + tl] = cvtpk(t0v, t1v);
            }
        }
        // no trailing sync: next iteration writes part[buf^1]
    }
}

// ================================================================ ifft stage 1 (over t): 512 blocks, direct CC reads
__global__ __launch_bounds__(256) void ifft1_mfma(const short* __restrict__ CC,
                                                  const short* __restrict__ F1P,
                                                  short* __restrict__ B2P) {
    __shared__ short st[32 * 64];    // 4 KB
    int bidx = blockIdx.x;           // 512: mt(64) x nt(8)
    int nt = bidx & 7;
    int mt = bidx >> 3;
    int bs0 = mt * 16;
    int b = mt >> 5;
    int kk2 = mt & 31;
    int tid = threadIdx.x, wid = tid >> 6, lane = tid & 63;
    int lrow = lane & 15, lg = lane >> 4;

    f32x4 acc[2];
    acc[0] = (f32x4){0.f, 0.f, 0.f, 0.f};
    acc[1] = (f32x4){0.f, 0.f, 0.f, 0.f};

    const short* arow = CC + (size_t)(bs0 + lrow) * 1024 + lg * 8;
    #pragma unroll 4
    for (int kk = 0; kk < 32; ++kk) {
        short8 a = *(const short8*)(arow + kk * 32);
        #pragma unroll
        for (int f = 0; f < 2; ++f) {
            int nfg = nt * 8 + wid * 2 + f;
            short8 bfr = *(const short8*)(F1P + ((kk * 64 + nfg) * 64 + lane) * 8);
            acc[f] = __builtin_amdgcn_mfma_f32_16x16x32_bf16(a, bfr, acc[f], 0, 0, 0);
        }
    }
    #pragma unroll
    for (int f = 0; f < 2; ++f)
        #pragma unroll
        for (int r = 0; r < 4; ++r) {
            int n_local = (wid * 2 + f) * 16 + lrow;    // 0..127
            int lq = n_local >> 1, d = n_local & 1;     // lq 0..63
            int lk = (lg * 4 + r) * 2 + d;              // 0..31
            st[lk * 64 + lq] = f2bf(acc[f][r]);
        }
    __syncthreads();
    {
        int f2 = wid;                                   // 0..3
        int nf2 = nt * 4 + f2;                          // 0..31
        short8 v;
        #pragma unroll
        for (int j = 0; j < 8; ++j)
            v[j] = st[((lane >> 4) * 8 + j) * 64 + f2 * 16 + (lane & 15)];
        *(short8*)(B2P + (size_t)b * 524288 + ((size_t)(kk2 * 32 + nf2) * 64 + lane) * 8) = v;
    }
}

// ================================================================ ifft stage 2 (over s) + scale/sigmoid: 512 blocks
__global__ __launch_bounds__(256) void ifft2_mfma(const short* __restrict__ B2P,
                                                  const short* __restrict__ F2,
                                                  const float* __restrict__ alpha, const float* __restrict__ beta,
                                                  float* __restrict__ out) {
    int bidx = blockIdx.x;           // 512: pt(32) x qt(8) x b(2)
    int pt_ = bidx & 31;
    int qt = (bidx >> 5) & 7;
    int b = bidx >> 8;
    int p0 = pt_ * 16;
    int tid = threadIdx.x, wid = tid >> 6, lane = tid & 63;
    int lrow = lane & 15, lg = lane >> 4;

    f32x4 acc = (f32x4){0.f, 0.f, 0.f, 0.f};

    const short* arow = F2 + (size_t)(p0 + lrow) * 1024 + lg * 8;
    const short* bbase = B2P + (size_t)b * 524288;
    int nfg = qt * 4 + wid;
    #pragma unroll 4
    for (int kk = 0; kk < 32; ++kk) {
        short8 a = *(const short8*)(arow + kk * 32);
        short8 bfr = *(const short8*)(bbase + ((size_t)(kk * 32 + nfg) * 64 + lane) * 8);
        acc = __builtin_amdgcn_mfma_f32_16x16x32_bf16(a, bfr, acc, 0, 0, 0);
    }
    float al = alpha[0], be = beta[0];
    const float scale = 1.0f / (512.0f * 512.0f);
    #pragma unroll
    for (int r = 0; r < 4; ++r) {
        int q = qt * 64 + wid * 16 + lrow;
        int p = p0 + lg * 4 + r;
        float l = al * (acc[r] * scale) + be;
        size_t idx = (size_t)b * 262144 + (size_t)p * 512 + q;
        out[idx] = l;
        out[524288 + idx] = 1.f / (1.f + expf(-l));
    }
}

// ================================================================ launch
extern "C" void kernel_launch(void* const* d_in, const int* in_sizes, int n_in,
                              void* d_out, int out_size, void* d_ws, size_t ws_size,
                              hipStream_t stream) {
    const float* spikes = (const float*)d_in[0];
    const float* Wr  = (const float*)d_in[1];
    const float* Wi  = (const float*)d_in[2];
    const float* pw1 = (const float*)d_in[3];
    const float* pb1 = (const float*)d_in[4];
    const float* pw2 = (const float*)d_in[5];
    const float* pb2 = (const float*)d_in[6];
    const float* nw1 = (const float*)d_in[7];
    const float* nb1 = (const float*)d_in[8];
    const float* nw2 = (const float*)d_in[9];
    const float* nb2 = (const float*)d_in[10];
    const float* sw  = (const float*)d_in[11];
    const float* sb  = (const float*)d_in[12];
    const float* tw_ = (const float*)d_in[13];
    const float* tb  = (const float*)d_in[14];
    const float* ew1 = (const float*)d_in[15];
    const float* eb1 = (const float*)d_in[16];
    const float* ew2 = (const float*)d_in[17];
    const float* eb2 = (const float*)d_in[18];
    const float* ew3 = (const float*)d_in[19];
    const float* eb3 = (const float*)d_in[20];
    const float* alpha = (const float*)d_in[21];
    const float* beta  = (const float*)d_in[22];
    float* out = (float*)d_out;
    float* ws  = (float*)d_ws;

    // region layout (floats):
    unsigned* CC    = (unsigned*)(ws + 0);        // [0, 524288): final CC (2 MB), overlays X64P
    float*    X64P  = ws + 0;                     // 8*65536 = 524288 f (dead after k_node)
    short*    WCP   = (short*)(ws + 524288);      // 65536 sh = 32768 f (dead after k_node)
    float*    BC    = ws + 557056;                // 512 f (dead after k_node)
    _Float16* PS16  = (_Float16*)(ws + 1048576);  // 131072 f (dead after edge)
    _Float16* PT16  = (_Float16*)(ws + 1179648);  // 131072 f (dead after edge)
    short*    B2P   = (short*)(ws + 1048576);     // 524288 f region [1048576, 1572864), overlays PS/PT
    _Float16* EW2H  = (_Float16*)(ws + 1572864);  // 16384 f
    short*    W4P   = (short*)(ws + 1589248);     // 131072 f
    short*    F1P   = (short*)(ws + 1720320);     // 524288 f
    short*    F2    = (short*)(ws + 2244608);     // 262144 f
    short*    PWP   = (short*)(ws + 2506752);     // 32768 f -> total 2539520 f (10.16 MB)

    setup_kernel<<<504, 256, 0, stream>>>(ew2, pw1, pw2, nw1, nw2, sw, tw_, sb, tb, ew1, eb1,
                                          W4P, F1P, F2, EW2H, PWP, WCP, BC);
    dft_mfma<<<512, 256, 0, stream>>>(spikes, W4P, X64P);
    k_node<<<128, 512, 0, stream>>>(X64P, Wr, Wi, PWP, pb1, pb2, nb1, nb2, WCP, BC, PS16, PT16);
    edge_mfma10<<<512, 512, 0, stream>>>(PS16, PT16, (const uint4*)EW2H, eb2, ew3, eb3, CC);
    ifft1_mfma<<<512, 256, 0, stream>>>((const short*)CC, F1P, B2P);
    ifft2_mfma<<<512, 256, 0, stream>>>(B2P, F2, alpha, beta, out);
}